// Round 6
// baseline (91.984 us; speedup 1.0000x reference)
//
#include <hip/hip_runtime.h>

// SNN forward, two kernels. Round-5 structure (best: 88.3 us) made PERSISTENT:
// grid = 1024 blocks (exactly 4 resident blocks/CU at ~96 VGPR) = 4096 waves;
// 8192 sixteen-row groups = exactly 2 groups per wave -> perfect static
// balance, no fractional dispatch rounds, no device-wide round-seam restart
// (R5: 2048 blocks in ~1.6-2 rounds => up to 25% idle capacity in the tail,
// matching the observed 5.0/6.3 TB/s = 0.8 deficit).
// Waves are independent after the one-time W load (no in-loop barriers), so
// persistence costs nothing. Bias preloaded to registers.
// GEMM per wave-group: 16 rows (4 slots x 4 rows), 16 f-lanes; W broadcast
// from LDS; x direct-to-VGPR coalesced 256 B segments; DPP 16-lane reduce.

#define T_STEPS 64
#define BATCH   2048
#define FEAT    784
#define OUT_N   10
#define ROWS    (T_STEPS * BATCH)     // 131072
#define NBLK    1024
#define NWAVES  (NBLK * 4)            // 4096
#define NGRP    (ROWS / 16)           // 8192 -> exactly 2 per wave

typedef __attribute__((ext_vector_type(4))) float f4;
typedef __attribute__((ext_vector_type(2))) float f2;

template <int CTRL>
__device__ __forceinline__ float dpp_mov(float v) {
    return __int_as_float(
        __builtin_amdgcn_update_dpp(0, __float_as_int(v), CTRL, 0xF, 0xF, true));
}
// sum over each aligned 16-lane group: xor1, xor2, xor7(half_mirror),
// xor15(mirror) generate the group — verified bit-exact on gfx950 (R4/R5).
__device__ __forceinline__ float red16(float v) {
    v += dpp_mov<0xB1>(v);    // quad_perm [1,0,3,2]  = xor 1
    v += dpp_mov<0x4E>(v);    // quad_perm [2,3,0,1]  = xor 2
    v += dpp_mov<0x141>(v);   // row_half_mirror      = xor 7
    v += dpp_mov<0x140>(v);   // row_mirror           = xor 15
    return v;
}

__global__ __launch_bounds__(256)
void snn_gemm(const float* __restrict__ x, const float* __restrict__ W,
              const float* __restrict__ bias, float* __restrict__ C) {
    __shared__ float Wl[OUT_N * FEAT];   // 31360 B

    {   // cooperative W load, vectorized (1960 float4s)
        const f4* Wg = (const f4*)W;
        f4* Ws = (f4*)Wl;
        for (int i = threadIdx.x; i < OUT_N * FEAT / 4; i += 256) Ws[i] = Wg[i];
    }
    __syncthreads();   // only barrier in the kernel

    const int tid = threadIdx.x;
    const int w   = tid >> 6;
    const int ln  = tid & 63;
    const int l16 = ln & 15;         // feature slice
    const int r   = ln >> 4;         // row slot
    const int wgid = blockIdx.x * 4 + w;   // 0..4095

    // preload bias as 5 x f2 (uniform, stays in SGPRs/VGPRs)
    f2 bv[5];
#pragma unroll
    for (int p = 0; p < 5; ++p) {
        bv[p].x = bias[2 * p];
        bv[p].y = bias[2 * p + 1];
    }

#pragma unroll 1
    for (int gi = 0; gi < 2; ++gi) {
        const int grp = wgid + gi * NWAVES;          // interleaved: balanced
        const long row0 = (long)grp * 16 + r * 4;
        const float* xbase = x + (size_t)row0 * FEAT + 4 * l16;

        float acc[4][OUT_N];
#pragma unroll
        for (int g = 0; g < 4; ++g)
#pragma unroll
            for (int o = 0; o < OUT_N; ++o) acc[g][o] = 0.0f;

        // prefetch chunk 0
        f4 cur[4];
#pragma unroll
        for (int g = 0; g < 4; ++g)
            cur[g] = *(const f4*)(xbase + (size_t)g * FEAT);

#pragma unroll 2
        for (int c = 0; c < 12; ++c) {
            f4 nxt[4];
            if (c < 11) {
#pragma unroll
                for (int g = 0; g < 4; ++g)
                    nxt[g] = *(const f4*)(xbase + (size_t)g * FEAT + (c + 1) * 64);
            }
#pragma unroll
            for (int o = 0; o < OUT_N; ++o) {
                const f4 wf = *(const f4*)&Wl[o * FEAT + c * 64 + l16 * 4];
#pragma unroll
                for (int g = 0; g < 4; ++g) {
                    acc[g][o] = fmaf(cur[g].x, wf.x, acc[g][o]);
                    acc[g][o] = fmaf(cur[g].y, wf.y, acc[g][o]);
                    acc[g][o] = fmaf(cur[g].z, wf.z, acc[g][o]);
                    acc[g][o] = fmaf(cur[g].w, wf.w, acc[g][o]);
                }
            }
            if (c < 11) {
#pragma unroll
                for (int g = 0; g < 4; ++g) cur[g] = nxt[g];
            }
        }

        // tail feats 768..783: lanes l16 < 4 add 4 floats each
        if (l16 < 4) {
#pragma unroll
            for (int g = 0; g < 4; ++g) {
                const f4 xt = *(const f4*)(xbase + (size_t)g * FEAT + 768);
#pragma unroll
                for (int o = 0; o < OUT_N; ++o) {
                    const f4 wf = *(const f4*)&Wl[o * FEAT + 768 + l16 * 4];
                    acc[g][o] = fmaf(xt.x, wf.x, acc[g][o]);
                    acc[g][o] = fmaf(xt.y, wf.y, acc[g][o]);
                    acc[g][o] = fmaf(xt.z, wf.z, acc[g][o]);
                    acc[g][o] = fmaf(xt.w, wf.w, acc[g][o]);
                }
            }
        }

        // reduce over the 16 f-lanes on the VALU pipe (DPP butterflies)
#pragma unroll
        for (int g = 0; g < 4; ++g)
#pragma unroll
            for (int o = 0; o < OUT_N; ++o) acc[g][o] = red16(acc[g][o]);

        if (l16 == 0) {
#pragma unroll
            for (int g = 0; g < 4; ++g) {
                float* Cr = C + (size_t)(row0 + g) * OUT_N;  // 40 B stride, 8-aligned
#pragma unroll
                for (int p = 0; p < 5; ++p) {
                    f2 s;
                    s.x = acc[g][2 * p]     + bv[p].x;
                    s.y = acc[g][2 * p + 1] + bv[p].y;
                    *(f2*)&Cr[2 * p] = s;
                }
            }
        }
    }
}

// Phase 2: one thread per (b, o); IF-neuron scan over t.
__global__ __launch_bounds__(256)
void snn_scan(const float* __restrict__ C, float* __restrict__ out) {
    const int idx = blockIdx.x * 256 + threadIdx.x;   // b*OUT_N + o
    if (idx >= BATCH * OUT_N) return;
    float v = 0.0f;
    float cnt = 0.0f;
#pragma unroll
    for (int t = 0; t < T_STEPS; ++t) {
        v += C[(size_t)t * BATCH * OUT_N + idx];
        if (v >= 1.0f) { cnt += 1.0f; v = 0.0f; }
    }
    out[idx] = cnt * (1.0f / 64.0f);
}

extern "C" void kernel_launch(void* const* d_in, const int* in_sizes, int n_in,
                              void* d_out, int out_size, void* d_ws, size_t ws_size,
                              hipStream_t stream) {
    const float* x    = (const float*)d_in[0];   // [64, 2048, 784] f32
    const float* W    = (const float*)d_in[1];   // [10, 784] f32
    const float* bias = (const float*)d_in[2];   // [10] f32
    float* out = (float*)d_out;                  // [2048, 10] f32
    float* C   = (float*)d_ws;                   // [131072, 10] f32 scratch

    snn_gemm<<<dim3(NBLK), dim3(256), 0, stream>>>(x, W, bias, C);
    snn_scan<<<dim3((BATCH * OUT_N + 255) / 256), dim3(256), 0, stream>>>(C, out);
}